// Round 4
// baseline (314.996 us; speedup 1.0000x reference)
//
#include <hip/hip_runtime.h>
#include <math.h>

#define SA 8      /* segments for kAll */
#define SEG2 8    /* segments for kM hist phase */
#define NB 4096
#define TAA 512   /* kAll threads */
#define HS 256    /* kAll histogram-scan owner threads */
#define TBB 1024  /* kM threads */
#define SCT 256   /* scan threads (R3-proven chunk structure) */
#define CH (NB / SCT) /* 16 */
#define CAPSEG 512
#define MAXM1 16
#define GB1 16384 /* gathered crossing-bin cap per mode-1 row */
#define SUBC 512  /* sub-bin cap */
#define EQC 64
#define FXS 1099511627776.0f /* 2^40 */
#define FXI (1.0f / 1099511627776.0f)

typedef unsigned u32;
typedef unsigned long long u64;

struct ScanSh {
  u32 axc[SCT]; float axe[SCT];
  u32 sufc[SCT]; float sufe[SCT];
  int cbin[SCT]; u32 cca[SCT]; float cea[SCT];
  int fbin[SCT]; u32 fca[SCT]; float fea[SCT];
};

__device__ __forceinline__ u32 f2key(float f) {
  u32 u = __float_as_uint(f);
  return u ^ ((u >> 31) ? 0xFFFFFFFFu : 0x80000000u);
}
__device__ __forceinline__ int is_mode0(int k, int V) {
  return (k >= 1 && k <= 256 && k < V);
}

// Deterministic slot = prefix count of mode-1 rows < row (parallel ballot-sum).
__device__ int m1_slot(const int* topks, int row, int V, int tid, int* red) {
  if (tid < 128) {
    int c = 0;
    for (int r = tid; r < row; r += 128) c += !is_mode0(topks[r], V);
    red[tid] = c;
  }
  __syncthreads();
  for (int s = 64; s > 0; s >>= 1) {
    if (tid < s) red[tid] += red[tid + s];
    __syncthreads();
  }
  return red[0];
}

__device__ __forceinline__ float row_max(const float* maxpart, int row) {
  float mm = maxpart[row * SA];
  for (int j = 1; j < SA; ++j) mm = fmaxf(mm, maxpart[row * SA + j]);
  return mm;
}

// R3-proven level-0 crossing scan, 256-owner structure.
__device__ void scan_level(const u32* cnt, const u64* e0, ScanSh* ax,
                           u32* sprefix, int* scnt_above, float* sexp_above,
                           float target, int tid) {
  if (tid < SCT) {
    u32 cc = 0; float ce = 0.f; const int base = tid * CH;
    for (int j = 0; j < CH; ++j) { cc += cnt[base + j]; ce += (float)e0[base + j] * FXI; }
    ax->axc[tid] = cc; ax->axe[tid] = ce;
  }
  __syncthreads();
  if (tid == 0) {
    u32 rc = 0; float re = 0.f;
    for (int c = SCT - 1; c >= 0; --c) {
      ax->sufc[c] = rc; ax->sufe[c] = re;
      rc += ax->axc[c]; re += ax->axe[c];
    }
  }
  __syncthreads();
  if (tid < SCT) {
    const int base = tid * CH;
    u32 rc = ax->sufc[tid]; float re = ax->sufe[tid];
    int best = -1; u32 bca = 0; float bea = 0.f;
    int fb = -1; u32 ffca = 0; float ffea = 0.f;
    for (int b = base + CH - 1; b >= base; --b) {
      u32 c = cnt[b]; float ebv = (float)e0[b] * FXI;
      bool cross = (c > 0) && ((re + ebv) >= target);
      if (cross && best < 0) { best = b; bca = rc; bea = re; }
      if (c > 0) { fb = b; ffca = rc; ffea = re; }
      rc += c; re += ebv;
    }
    ax->cbin[tid] = best; ax->cca[tid] = bca; ax->cea[tid] = bea;
    ax->fbin[tid] = fb; ax->fca[tid] = ffca; ax->fea[tid] = ffea;
  }
  __syncthreads();
  if (tid == 0) {
    int bsel = -1; u32 ca = 0; float ea = 0.f;
    for (int c = 0; c < SCT; ++c) {
      int b = ax->cbin[c];
      if (b > bsel) { bsel = b; ca = ax->cca[c]; ea = ax->cea[c]; }
    }
    if (bsel < 0) {
      for (int c = 0; c < SCT; ++c) {
        int b = ax->fbin[c];
        if (b >= 0 && (bsel < 0 || b < bsel)) { bsel = b; ca = ax->fca[c]; ea = ax->fea[c]; }
      }
    }
    if (bsel < 0) bsel = 0;
    *sprefix = (u32)bsel;
    *scnt_above = (int)ca;
    *sexp_above = ea;
  }
  __syncthreads();
}

// kAll: per-(row,seg) seg max (all rows); mode-0 rows: hist + top-k-bin T +
// candidate gather (atomicExch, device-scope) + arrival counter; the LAST
// arriver per mode-0 row runs the full kH finisher (radix-select, sort,
// replay, race) with atomic readbacks -> writes out[row]. Mode-1 rows exit
// after the max (kM handles them; maxpart crosses the kernel boundary).
__global__ __launch_bounds__(TAA) void kAll(const float* __restrict__ logits,
                                            const float* __restrict__ temps,
                                            const int* __restrict__ topks,
                                            const float* __restrict__ topps,
                                            const float* __restrict__ noise,
                                            float* __restrict__ maxpart,
                                            u32* __restrict__ scnt,
                                            float* __restrict__ candv,
                                            int* __restrict__ candi,
                                            u32* __restrict__ rdoneA,
                                            int* __restrict__ out, int V) {
  const int row = blockIdx.x, seg = blockIdx.y, tid = threadIdx.x;
  __shared__ u32 cnt[NB];
  __shared__ float sm[TAA];
  __shared__ u32 cs[HS];
  __shared__ int bb[HS];
  __shared__ int lcnt;
  __shared__ u32 sT;
  const int kR = topks[row];
  const int m0 = is_mode0(kR, V);
  const float t = temps[row];
  const float* lr = logits + (size_t)row * V;
  const float4* l4 = (const float4*)lr;
  const int n4 = V >> 2;
  const int q0 = (int)((long long)seg * n4 / SA);
  const int q1 = (int)((long long)(seg + 1) * n4 / SA);
  float mx = -INFINITY;
  if (m0) {
    for (int i = tid; i < NB; i += TAA) cnt[i] = 0;
    if (tid == 0) lcnt = 0;
    __syncthreads();
    for (int i = q0 + tid; i < q1; i += TAA) {
      float4 v = l4[i];
      float xs[4] = {v.x / t, v.y / t, v.z / t, v.w / t};
#pragma unroll
      for (int j = 0; j < 4; ++j) {
        mx = fmaxf(mx, xs[j]);
        atomicAdd(&cnt[f2key(xs[j]) >> 20], 1u);
      }
    }
    if (seg == SA - 1)
      for (int i = (n4 << 2) + tid; i < V; i += TAA) {
        float x = lr[i] / t;
        mx = fmaxf(mx, x);
        atomicAdd(&cnt[f2key(x) >> 20], 1u);
      }
  } else {
    for (int i = q0 + tid; i < q1; i += TAA) {
      float4 v = l4[i];
      mx = fmaxf(mx, fmaxf(fmaxf(v.x, v.y), fmaxf(v.z, v.w)) / t);
    }
    if (seg == SA - 1)
      for (int i = (n4 << 2) + tid; i < V; i += TAA) mx = fmaxf(mx, lr[i] / t);
  }
  sm[tid] = mx;
  __syncthreads();
  for (int s = TAA >> 1; s > 0; s >>= 1) {
    if (tid < s) sm[tid] = fmaxf(sm[tid], sm[tid + s]);
    __syncthreads();
  }
  if (tid == 0)
    atomicExch((u32*)&maxpart[row * SA + seg], __float_as_uint(sm[0]));
  if (!m0) return;
  if (tid < HS) {
    u32 cc = 0; const int base = tid * (NB / HS);
    for (int j = 0; j < NB / HS; ++j) cc += cnt[base + j];
    cs[tid] = cc;
  }
  __syncthreads();
  if (tid == 0) {
    u32 rc = 0;
    for (int c = HS - 1; c >= 0; --c) { u32 tmp = cs[c]; cs[c] = rc; rc += tmp; }
  }
  __syncthreads();
  const int kk0 = (kR > 256) ? 256 : kR;
  if (tid < HS) {
    const int base = tid * (NB / HS);
    u32 rc = cs[tid]; int best = -1;
    for (int b = base + NB / HS - 1; b >= base; --b) {
      u32 c = cnt[b];
      if (c && best < 0 && (int)(rc + c) >= kk0) best = b;
      rc += c;
    }
    bb[tid] = best;
  }
  __syncthreads();
  if (tid == 0) {
    int bsel = -1;
    for (int c = 0; c < HS; ++c) if (bb[c] > bsel) bsel = bb[c];
    if (bsel < 0) { for (int b = 0; b < NB; ++b) if (cnt[b]) { bsel = b; break; } }
    if (bsel < 0) bsel = 0;
    sT = ((u32)bsel) << 20;
  }
  __syncthreads();
  const u32 T = sT;
  const size_t cbase = ((size_t)row * SA + seg) * CAPSEG;
  for (int i = q0 + tid; i < q1; i += TAA) {
    float4 v = l4[i];
    float xs[4] = {v.x / t, v.y / t, v.z / t, v.w / t};
#pragma unroll
    for (int j = 0; j < 4; ++j) {
      if (f2key(xs[j]) >= T) {
        int s = atomicAdd(&lcnt, 1);
        if (s < CAPSEG) {
          atomicExch((u32*)&candv[cbase + s], __float_as_uint(xs[j]));
          atomicExch((u32*)&candi[cbase + s], (u32)(i * 4 + j));
        }
      }
    }
  }
  if (seg == SA - 1)
    for (int i = (n4 << 2) + tid; i < V; i += TAA) {
      float x = lr[i] / t;
      if (f2key(x) >= T) {
        int s = atomicAdd(&lcnt, 1);
        if (s < CAPSEG) {
          atomicExch((u32*)&candv[cbase + s], __float_as_uint(x));
          atomicExch((u32*)&candi[cbase + s], (u32)i);
        }
      }
    }
  __syncthreads();
  __shared__ int slast;
  if (tid == 0) {
    int n = lcnt; if (n > CAPSEG) n = CAPSEG;
    atomicExch(&scnt[row * SA + seg], (u32)n);
    __threadfence();  // release: all this block's atomics before arrival
    u32 arr = atomicAdd(&rdoneA[row], 1u);
    slast = (arr == (u32)(SA - 1)) ? 1 : 0;
  }
  __syncthreads();
  if (!slast) return;
  __threadfence();  // acquire

  // ---- mode-0 finisher (old kH body; candidates -> registers) ----
  __shared__ float fv[CAPSEG]; __shared__ int fi[CAPSEG];
  __shared__ float sv[CAPSEG]; __shared__ int si[CAPSEG];
  __shared__ float pe[CAPSEG];
  __shared__ float rrf[TAA]; __shared__ int rif[TAA];
  __shared__ int offs[SA + 1];
  __shared__ u32 dh[256]; __shared__ u32 dsufx[256];
  __shared__ u32 sPrefix; __shared__ int sRemain, sNf, sDig;
  __shared__ int sJ; __shared__ float sZ2, sM;
  if (tid == 0) {
    int o = 0;
    for (int s = 0; s < SA; ++s) {
      offs[s] = o;
      int c = (int)atomicAdd(&scnt[row * SA + s], 0u);
      if (c > CAPSEG) c = CAPSEG;
      if (c < 0) c = 0;
      o += c;
    }
    offs[SA] = o;
    float mm = __uint_as_float(atomicAdd((u32*)&maxpart[row * SA], 0u));
    for (int j = 1; j < SA; ++j)
      mm = fmaxf(mm, __uint_as_float(atomicAdd((u32*)&maxpart[row * SA + j], 0u)));
    sM = mm;
    int kk = kR; if (kk > 256) kk = 256; if (kk > o) kk = o;
    sPrefix = 0u; sRemain = (kk < 1) ? 1 : kk;
  }
  __syncthreads();
  const int g = offs[SA];
  float rv[8]; int rix[8];
#pragma unroll
  for (int c = 0; c < 8; ++c) {
    const int i = tid + c * TAA;
    rv[c] = 0.f; rix[c] = -1;
    if (i < g) {
      int s = 0;
      while (i >= offs[s + 1]) ++s;
      const size_t cb2 = ((size_t)row * SA + s) * CAPSEG + (size_t)(i - offs[s]);
      rv[c] = __uint_as_float(atomicAdd((u32*)&candv[cb2], 0u));
      rix[c] = (int)atomicAdd((u32*)&candi[cb2], 0u);
    }
  }
  for (int pass = 0; pass < 4; ++pass) {
    const int shift = 24 - 8 * pass;
    if (tid < 256) dh[tid] = 0;
    if (tid == 0) sDig = -1;
    __syncthreads();
    const u32 pref = sPrefix;
#pragma unroll
    for (int c = 0; c < 8; ++c) {
      if (rix[c] >= 0) {
        u32 key = f2key(rv[c]);
        if (pass == 0 || (key >> (shift + 8)) == pref)
          atomicAdd(&dh[(key >> shift) & 0xFFu], 1u);
      }
    }
    __syncthreads();
    if (tid < 256) dsufx[tid] = dh[tid];
    __syncthreads();
    for (int stp = 1; stp < 256; stp <<= 1) {
      u32 addv = 0;
      if (tid < 256 && tid + stp < 256) addv = dsufx[tid + stp];
      __syncthreads();
      if (tid < 256) dsufx[tid] += addv;
      __syncthreads();
    }
    if (tid < 256) {
      u32 excl = dsufx[tid] - dh[tid];
      u32 rem = (u32)sRemain;
      if (dh[tid] && excl < rem && excl + dh[tid] >= rem) sDig = tid;  // unique
    }
    __syncthreads();
    if (tid == 0) {
      int d = sDig; if (d < 0) d = 0;
      u32 excl = dsufx[d] - dh[d];
      sRemain -= (int)excl;
      sPrefix = (sPrefix << 8) | (u32)d;
      if (pass == 3) sNf = 0;
    }
    __syncthreads();
  }
  const u32 Tk = sPrefix;
#pragma unroll
  for (int c = 0; c < 8; ++c) {
    if (rix[c] >= 0 && f2key(rv[c]) >= Tk) {
      int s = atomicAdd(&sNf, 1);
      if (s < CAPSEG) { fv[s] = rv[c]; fi[s] = rix[c]; }
    }
  }
  __syncthreads();
  int nf = sNf; if (nf > CAPSEG) nf = CAPSEG;
  for (int i = tid; i < nf; i += TAA) {
    float v = fv[i]; int ix = fi[i];
    int rank = 0;
    for (int j = 0; j < nf; ++j) {
      float vj = fv[j]; int ij = fi[j];
      if (vj > v || (vj == v && ij < ix)) rank++;
    }
    sv[rank] = v; si[rank] = ix;
  }
  __syncthreads();
  const float m = sM;
  const float p = topps[row];
  int keff = kR; if (keff > nf) keff = nf;
  for (int j = tid; j < keff; j += TAA) pe[j] = expf(sv[j] - m);
  __syncthreads();
  if (tid == 0) {
    int J = 1; float Z2 = 1.f;
    if (nf > 0 && keff > 0) {
      float Zk = 0.f;
      for (int j = 0; j < keff; ++j) Zk += pe[j];
      float c = 0.f; int Jc = 0;
      for (int j = 0; j < keff; ++j) {  // no break: cumsum non-decreasing
        float pr = pe[j] / Zk;
        c += pr;
        if (c < p) Jc++;
      }
      if (Jc < 1) Jc = 1;
      J = Jc;
      Z2 = 0.f;
      for (int j = 0; j < J && j < keff; ++j) Z2 += pe[j];
    }
    sJ = J; sZ2 = Z2;
  }
  __syncthreads();
  const int J = sJ; const float Z2 = sZ2;
  const float* ur = noise + (size_t)row * V;
  float best = -1.f; int bidx = 0x7FFFFFFF;
  for (int j = tid; j < J && j < nf; j += TAA) {
    int ix = si[j];
    float u = ur[ix];
    float q = fmaxf(-logf(u), 1e-10f);
    float pr = pe[j] / Z2;
    float rt = pr / q;
    if (rt > best || (rt == best && ix < bidx)) { best = rt; bidx = ix; }
  }
  rrf[tid] = best; rif[tid] = bidx;
  __syncthreads();
  for (int s = TAA >> 1; s > 0; s >>= 1) {
    if (tid < s) {
      float ov = rrf[tid + s]; int oi = rif[tid + s];
      if (ov > rrf[tid] || (ov == rrf[tid] && oi < rif[tid])) { rrf[tid] = ov; rif[tid] = oi; }
    }
    __syncthreads();
  }
  if (tid == 0) out[row] = (nf > 0) ? rif[0] : 0;
}

// kM: mode-1 rows only. Seg blocks: level-0 hist (LDS) -> atomicAdd flush to
// global accumulators + S partial (atomicExch) -> arrival. LAST arriver:
// atomic-readback summed hist, crossing scan, then SOLO: gather crossing bin
// (block-private global scratch), 10-bit sub-scan, rank-sort, exact replay,
// full-row race -> out[row]. Everything cross-block is atomic-written/read.
__global__ __launch_bounds__(TBB) void kM(const float* __restrict__ logits,
                                          const float* __restrict__ temps,
                                          const int* __restrict__ topks,
                                          const float* __restrict__ topps,
                                          const float* __restrict__ noise,
                                          const float* __restrict__ maxpart,
                                          float* __restrict__ Sparts,
                                          u32* __restrict__ m1c0,
                                          u64* __restrict__ m1e0,
                                          u64* __restrict__ g1p,
                                          u32* __restrict__ rdoneM,
                                          int* __restrict__ out, int V) {
  const int row = blockIdx.x, seg = blockIdx.y, tid = threadIdx.x;
  const int k = topks[row];
  if (is_mode0(k, V)) return;
  __shared__ int red[128];
  const int slot = m1_slot(topks, row, V, tid, red);
  if (slot >= MAXM1) return;

  __shared__ u32 cnt[NB];      // 16KB (seg hist, reused for readback)
  __shared__ u64 e0[NB];       // 32KB
  __shared__ float ss[TBB];    // 4KB
  const float t = temps[row];
  const float m = row_max(maxpart, row);  // cross-kernel, plain read (order-preserving)
  const float* lr = logits + (size_t)row * V;
  const float* ur = noise + (size_t)row * V;
  const float4* l4 = (const float4*)lr;
  const int n4 = V >> 2;
  const int q0 = (int)((long long)seg * n4 / SEG2);
  const int q1 = (int)((long long)(seg + 1) * n4 / SEG2);

  // ---- seg hist phase (old kE body) ----
  for (int i = tid; i < NB; i += TBB) { cnt[i] = 0; e0[i] = 0ull; }
  __syncthreads();
  float ls = 0.f;
  for (int i = q0 + tid; i < q1; i += TBB) {
    float4 v = l4[i];
    float xs[4] = {v.x / t, v.y / t, v.z / t, v.w / t};
#pragma unroll
    for (int j = 0; j < 4; ++j) {
      float e = expf(xs[j] - m);
      ls += e;
      u32 b = f2key(xs[j]) >> 20;
      atomicAdd(&cnt[b], 1u);
      u64 fx = (u64)(e * FXS);
      if (fx) atomicAdd(&e0[b], fx);
    }
  }
  if (seg == SEG2 - 1)
    for (int i = (n4 << 2) + tid; i < V; i += TBB) {
      float x = lr[i] / t;
      float e = expf(x - m);
      ls += e;
      u32 b = f2key(x) >> 20;
      atomicAdd(&cnt[b], 1u);
      u64 fx = (u64)(e * FXS);
      if (fx) atomicAdd(&e0[b], fx);
    }
  ss[tid] = ls;
  __syncthreads();
  for (int s = TBB >> 1; s > 0; s >>= 1) {
    if (tid < s) ss[tid] += ss[tid + s];
    __syncthreads();
  }
  if (tid == 0)
    atomicExch((u32*)&Sparts[slot * SEG2 + seg], __float_as_uint(ss[0]));
  for (int b = tid; b < NB; b += TBB) {
    u32 c = cnt[b]; if (c) atomicAdd(&m1c0[(size_t)slot * NB + b], c);
    u64 e = e0[b]; if (e) atomicAdd(&m1e0[(size_t)slot * NB + b], e);
  }
  __syncthreads();
  __shared__ int slast;
  if (tid == 0) {
    __threadfence();  // release
    u32 arr = atomicAdd(&rdoneM[row], 1u);
    slast = (arr == (u32)(SEG2 - 1)) ? 1 : 0;
  }
  __syncthreads();
  if (!slast) return;
  __threadfence();  // acquire

  // ---- finisher: readback summed hist, scan, solo gather/replay/race ----
  __shared__ ScanSh ax;        // 10KB
  __shared__ u32 cnt1[1024]; __shared__ u64 fx1[1024];   // 12KB
  __shared__ u32 csuf[1024]; __shared__ u64 esuf[1024];  // 12KB
  __shared__ float subv[SUBC]; __shared__ int subi[SUBC];
  __shared__ float ssv[SUBC]; __shared__ int ssi[SUBC];  // 8KB
  __shared__ float rr[TBB]; __shared__ int ri[TBB];      // 8KB
  __shared__ int eqs[EQC];
  __shared__ u32 spfx; __shared__ int sca; __shared__ float sea;
  __shared__ float sS;
  __shared__ int sgc, scross, sfb, sca1, sns, seqn;
  __shared__ float sea1; __shared__ u32 svstar;

  for (int i = tid; i < NB; i += TBB) {
    cnt[i] = atomicAdd(&m1c0[(size_t)slot * NB + i], 0u);
    e0[i] = atomicAdd(&m1e0[(size_t)slot * NB + i], 0ull);
  }
  if (tid == 0) {
    float S = 0.f;
    for (int j = 0; j < SEG2; ++j)
      S += __uint_as_float(atomicAdd((u32*)&Sparts[slot * SEG2 + j], 0u));
    sS = S;
    sgc = 0; sns = 0; scross = -1; sfb = 0x7FFFFFFF;
  }
  __syncthreads();
  const float S = sS;
  const float target = topps[row] * S;
  scan_level(cnt, e0, &ax, &spfx, &sca, &sea, target, tid);
  const u32 pfx = spfx;

  // solo gather of crossing-bin elements (block-private scratch, plain I/O)
  const size_t gbase = (size_t)slot * GB1;
  for (int i = tid; i < n4; i += TBB) {
    float4 v = l4[i];
    float xs[4] = {v.x / t, v.y / t, v.z / t, v.w / t};
#pragma unroll
    for (int j = 0; j < 4; ++j) {
      if ((f2key(xs[j]) >> 20) == pfx) {
        int s2 = atomicAdd(&sgc, 1);
        if (s2 < GB1)
          g1p[gbase + s2] = ((u64)__float_as_uint(xs[j]) << 32) | (u64)(u32)(i * 4 + j);
      }
    }
  }
  for (int i = (n4 << 2) + tid; i < V; i += TBB) {
    float x = lr[i] / t;
    if ((f2key(x) >> 20) == pfx) {
      int s2 = atomicAdd(&sgc, 1);
      if (s2 < GB1)
        g1p[gbase + s2] = ((u64)__float_as_uint(x) << 32) | (u64)(u32)i;
    }
  }
  __syncthreads();  // block-level global visibility for same-block readers
  int nf = sgc; if (nf > GB1) nf = GB1;

  // 10-bit sub-hist + exact suffix sums + crossing sub-bin
  cnt1[tid] = 0; fx1[tid] = 0ull;
  __syncthreads();
  for (int i = tid; i < nf; i += TBB) {
    u64 pk = g1p[gbase + i];
    float x = __uint_as_float((u32)(pk >> 32));
    u32 b = (f2key(x) >> 10) & 0x3FFu;
    float e = expf(x - m);
    atomicAdd(&cnt1[b], 1u);
    u64 fx = (u64)(e * FXS);
    if (fx) atomicAdd(&fx1[b], fx);
  }
  __syncthreads();
  csuf[tid] = cnt1[tid]; esuf[tid] = fx1[tid];
  __syncthreads();
  for (int stp = 1; stp < 1024; stp <<= 1) {
    u32 ca_ = 0; u64 ea_ = 0ull;
    if (tid + stp < 1024) { ca_ = csuf[tid + stp]; ea_ = esuf[tid + stp]; }
    __syncthreads();
    csuf[tid] += ca_; esuf[tid] += ea_;
    __syncthreads();
  }
  {
    u32 c = cnt1[tid];
    if (c) {
      float racc = (float)(esuf[tid] - fx1[tid]) * FXI;  // exact suffix above bin
      float ebv = (float)fx1[tid] * FXI;
      if (sea + (racc + ebv) >= target) atomicMax(&scross, tid);
      atomicMin(&sfb, tid);
    }
  }
  __syncthreads();
  if (tid == 0) {
    int cb = scross;
    if (cb < 0) cb = (sfb != 0x7FFFFFFF) ? sfb : 0;
    u32 cAbove = csuf[cb] - cnt1[cb];
    float eAbove = (float)(esuf[cb] - fx1[cb]) * FXI;
    scross = cb;
    sea1 = sea + eAbove;
    sca1 = sca + (int)cAbove;
  }
  __syncthreads();
  const u32 cb = (u32)scross;
  for (int i = tid; i < nf; i += TBB) {
    u64 pk = g1p[gbase + i];
    float x = __uint_as_float((u32)(pk >> 32));
    if (((f2key(x) >> 10) & 0x3FFu) == cb) {
      int s2 = atomicAdd(&sns, 1);
      if (s2 < SUBC) { subv[s2] = x; subi[s2] = (int)(u32)(pk & 0xFFFFFFFFull); }
    }
  }
  __syncthreads();
  int ns = sns; if (ns > SUBC) ns = SUBC;
  for (int i = tid; i < ns; i += TBB) {
    float v = subv[i]; int ix = subi[i];
    int rank = 0;
    for (int j2 = 0; j2 < ns; ++j2) {
      float vj = subv[j2]; int ij = subi[j2];
      if (vj > v || (vj == v && ij < ix)) rank++;
    }
    ssv[rank] = v; ssi[rank] = ix;
  }
  __syncthreads();
  if (tid == 0) {
    const float p = topps[row];
    float run_n = sea1 / S;
    const int have_above = (sca1 > 0);
    u32 lastkey = 0u; int lastr = 0, laststart = -1, anykept = 0;
    u32 vsel = 0u; int rsel = -1, bstart = 0;
    int j = 0;
    while (j < ns) {
      u32 key = f2key(ssv[j]);
      int c = 1;
      while (j + c < ns && f2key(ssv[j + c]) == key) ++c;
      float e = expf(ssv[j] - m);
      float en = e / S;
      int kept = 0;
      for (int q = 0; q < c; ++q) {
        float nn = run_n + en;
        if (nn < p) { run_n = nn; kept++; } else break;
      }
      if (kept == c) { lastkey = key; lastr = c; laststart = j; anykept = 1; j += c; continue; }
      if (kept > 0) { vsel = key; rsel = kept; bstart = j; }
      else if (anykept) { vsel = lastkey; rsel = lastr; bstart = laststart; }
      else if (have_above) { vsel = key; rsel = 0; bstart = j; }
      else { vsel = key; rsel = 1; bstart = j; }
      break;
    }
    if (rsel < 0) {
      if (anykept) { vsel = lastkey; rsel = lastr; bstart = laststart; }
      else if (ns > 0) {
        vsel = f2key(ssv[0]); bstart = 0;
        rsel = have_above ? 0 : 1;
      } else { vsel = 0u; rsel = 0; bstart = 0; }
    }
    int eqn = rsel;
    if (eqn > EQC) eqn = EQC;
    if (eqn < 0) eqn = 0;
    if (bstart + eqn > ns) eqn = ns - bstart;
    if (eqn < 0) eqn = 0;
    for (int q2 = 0; q2 < eqn; ++q2) eqs[q2] = ssi[bstart + q2];
    seqn = eqn; svstar = vsel;
  }
  __syncthreads();

  // solo full-row race (Z2 constant factor dropped - argmax invariant)
  const u32 vk = svstar;
  const int eqn = seqn;
  const float4* u4 = (const float4*)ur;
  float best = -1.f; int bidx = 0x7FFFFFFF;
  for (int i = tid; i < n4; i += TBB) {
    float4 xv = l4[i];
    float4 uv = u4[i];
    float xs[4] = {xv.x / t, xv.y / t, xv.z / t, xv.w / t};
    float us[4] = {uv.x, uv.y, uv.z, uv.w};
#pragma unroll
    for (int j = 0; j < 4; ++j) {
      u32 key = f2key(xs[j]);
      bool kept = key > vk;
      if (!kept && key == vk) {
        int idx = i * 4 + j;
        for (int e = 0; e < eqn; ++e) if (eqs[e] == idx) { kept = true; break; }
      }
      if (kept) {
        float q = fmaxf(-logf(us[j]), 1e-10f);
        float rt = expf(xs[j] - m) / q;
        int idx = i * 4 + j;
        if (rt > best || (rt == best && idx < bidx)) { best = rt; bidx = idx; }
      }
    }
  }
  for (int i = (n4 << 2) + tid; i < V; i += TBB) {
    float x = lr[i] / t;
    u32 key = f2key(x);
    bool kept = key > vk;
    if (!kept && key == vk) {
      for (int e = 0; e < eqn; ++e) if (eqs[e] == i) { kept = true; break; }
    }
    if (kept) {
      float q = fmaxf(-logf(ur[i]), 1e-10f);
      float rt = expf(x - m) / q;
      if (rt > best || (rt == best && i < bidx)) { best = rt; bidx = i; }
    }
  }
  rr[tid] = best; ri[tid] = bidx;
  __syncthreads();
  for (int s = TBB >> 1; s > 0; s >>= 1) {
    if (tid < s) {
      float ov = rr[tid + s]; int oi = ri[tid + s];
      if (ov > rr[tid] || (ov == rr[tid] && oi < ri[tid])) { rr[tid] = ov; ri[tid] = oi; }
    }
    __syncthreads();
  }
  if (tid == 0) out[row] = (rr[0] >= 0.f) ? ri[0] : 0;
}

extern "C" void kernel_launch(void* const* d_in, const int* in_sizes, int n_in,
                              void* d_out, int out_size, void* d_ws, size_t ws_size,
                              hipStream_t stream) {
  const float* logits = (const float*)d_in[0];
  const float* temps = (const float*)d_in[1];
  const int* topks = (const int*)d_in[2];
  const float* topps = (const float*)d_in[3];
  const float* noise = (const float*)d_in[4];
  int* out = (int*)d_out;
  const int B = in_sizes[1];
  const int V = in_sizes[0] / B;
  (void)n_in; (void)out_size; (void)ws_size;

  u32* w = (u32*)d_ws;
  size_t o = 0;
  float* maxpart = (float*)(w + o); o += (size_t)B * SA;
  u32* scnt = w + o; o += (size_t)B * SA;
  float* candv = (float*)(w + o); o += (size_t)B * SA * CAPSEG;
  int* candi = (int*)(w + o); o += (size_t)B * SA * CAPSEG;
  if (o & 1) o += 1;
  const size_t zbase = o;                      // zeroed region (hipMemsetAsync)
  u64* m1e0 = (u64*)(w + o); o += 2 * (size_t)MAXM1 * NB;
  u32* m1c0 = w + o; o += (size_t)MAXM1 * NB;
  u32* rdoneA = w + o; o += (size_t)B;
  u32* rdoneM = w + o; o += (size_t)B;
  const size_t zwords = o - zbase;
  float* Sparts = (float*)(w + o); o += (size_t)MAXM1 * SEG2;
  if (o & 1) o += 1;
  u64* g1p = (u64*)(w + o); o += 2 * (size_t)MAXM1 * GB1;

  hipMemsetAsync((void*)(w + zbase), 0, zwords * sizeof(u32), stream);
  kAll<<<dim3(B, SA), TAA, 0, stream>>>(logits, temps, topks, topps, noise,
                                        maxpart, scnt, candv, candi, rdoneA, out, V);
  kM<<<dim3(B, SEG2), TBB, 0, stream>>>(logits, temps, topks, topps, noise, maxpart,
                                        Sparts, m1c0, m1e0, g1p, rdoneM, out, V);
}

// Round 5
// 260.798 us; speedup vs baseline: 1.2078x; 1.2078x over previous
//
#include <hip/hip_runtime.h>
#include <math.h>

#define SA 8      /* segments for kA */
#define SEG2 8    /* segments for kM hist phase */
#define NB 4096
#define TAA 512   /* kA threads */
#define HS 256    /* kA histogram-scan owner threads */
#define TBB 1024  /* kH / kM threads */
#define SCT 256   /* scan threads (R3-proven chunk structure) */
#define CH (NB / SCT) /* 16 */
#define CAPSEG 512
#define GTOT (SA * CAPSEG) /* 4096 */
#define MAXM1 16
#define SUBC 512  /* sub-bin cap */
#define EQC 64
#define FXS 1099511627776.0f /* 2^40 */
#define FXI (1.0f / 1099511627776.0f)

typedef unsigned u32;
typedef unsigned long long u64;

struct ScanSh {
  u32 axc[SCT]; float axe[SCT];
  u32 sufc[SCT]; float sufe[SCT];
  int cbin[SCT]; u32 cca[SCT]; float cea[SCT];
  int fbin[SCT]; u32 fca[SCT]; float fea[SCT];
};

__device__ __forceinline__ u32 f2key(float f) {
  u32 u = __float_as_uint(f);
  return u ^ ((u >> 31) ? 0xFFFFFFFFu : 0x80000000u);
}
__device__ __forceinline__ int is_mode0(int k, int V) {
  return (k >= 1 && k <= 256 && k < V);
}

// Deterministic slot = prefix count of mode-1 rows < row (parallel ballot-sum).
__device__ int m1_slot(const int* topks, int row, int V, int tid, int* red) {
  if (tid < 128) {
    int c = 0;
    for (int r = tid; r < row; r += 128) c += !is_mode0(topks[r], V);
    red[tid] = c;
  }
  __syncthreads();
  for (int s = 64; s > 0; s >>= 1) {
    if (tid < s) red[tid] += red[tid + s];
    __syncthreads();
  }
  return red[0];
}

__device__ __forceinline__ float row_max(const float* maxpart, int row) {
  float mm = maxpart[row * SA];
  for (int j = 1; j < SA; ++j) mm = fmaxf(mm, maxpart[row * SA + j]);
  return mm;
}

// R3-proven level-0 crossing scan, 256-owner structure.
__device__ void scan_level(const u32* cnt, const u64* e0, ScanSh* ax,
                           u32* sprefix, int* scnt_above, float* sexp_above,
                           float target, int tid) {
  if (tid < SCT) {
    u32 cc = 0; float ce = 0.f; const int base = tid * CH;
    for (int j = 0; j < CH; ++j) { cc += cnt[base + j]; ce += (float)e0[base + j] * FXI; }
    ax->axc[tid] = cc; ax->axe[tid] = ce;
  }
  __syncthreads();
  if (tid == 0) {
    u32 rc = 0; float re = 0.f;
    for (int c = SCT - 1; c >= 0; --c) {
      ax->sufc[c] = rc; ax->sufe[c] = re;
      rc += ax->axc[c]; re += ax->axe[c];
    }
  }
  __syncthreads();
  if (tid < SCT) {
    const int base = tid * CH;
    u32 rc = ax->sufc[tid]; float re = ax->sufe[tid];
    int best = -1; u32 bca = 0; float bea = 0.f;
    int fb = -1; u32 ffca = 0; float ffea = 0.f;
    for (int b = base + CH - 1; b >= base; --b) {
      u32 c = cnt[b]; float ebv = (float)e0[b] * FXI;
      bool cross = (c > 0) && ((re + ebv) >= target);
      if (cross && best < 0) { best = b; bca = rc; bea = re; }
      if (c > 0) { fb = b; ffca = rc; ffea = re; }
      rc += c; re += ebv;
    }
    ax->cbin[tid] = best; ax->cca[tid] = bca; ax->cea[tid] = bea;
    ax->fbin[tid] = fb; ax->fca[tid] = ffca; ax->fea[tid] = ffea;
  }
  __syncthreads();
  if (tid == 0) {
    int bsel = -1; u32 ca = 0; float ea = 0.f;
    for (int c = 0; c < SCT; ++c) {
      int b = ax->cbin[c];
      if (b > bsel) { bsel = b; ca = ax->cca[c]; ea = ax->cea[c]; }
    }
    if (bsel < 0) {
      for (int c = 0; c < SCT; ++c) {
        int b = ax->fbin[c];
        if (b >= 0 && (bsel < 0 || b < bsel)) { bsel = b; ca = ax->fca[c]; ea = ax->fea[c]; }
      }
    }
    if (bsel < 0) bsel = 0;
    *sprefix = (u32)bsel;
    *scnt_above = (int)ca;
    *sexp_above = ea;
  }
  __syncthreads();
}

// kA: R3-proven body (plain candidate stores; kernel boundary provides
// coherence for kH). Adds: grid-stride zeroing of kM's accumulators
// (replaces the hipMemsetAsync dispatch).
__global__ __launch_bounds__(TAA) void kA(const float* __restrict__ logits,
                                          const float* __restrict__ temps,
                                          const int* __restrict__ topks,
                                          float* __restrict__ maxpart,
                                          u32* __restrict__ scnt,
                                          float* __restrict__ candv,
                                          int* __restrict__ candi,
                                          u32* __restrict__ zp, size_t zwords,
                                          int V) {
  const int row = blockIdx.x, seg = blockIdx.y, tid = threadIdx.x;
  __shared__ u32 cnt[NB];
  __shared__ float sm[TAA];
  __shared__ u32 cs[HS];
  __shared__ int bb[HS];
  __shared__ int lcnt;
  __shared__ u32 sT;
  {
    const size_t gid = ((size_t)blockIdx.y * gridDim.x + blockIdx.x) * TAA + tid;
    const size_t stride = (size_t)gridDim.x * gridDim.y * TAA;
    for (size_t i = gid; i < zwords; i += stride) zp[i] = 0;
  }
  const int k = topks[row];
  const int m0 = is_mode0(k, V);
  const float t = temps[row];
  const float* lr = logits + (size_t)row * V;
  const float4* l4 = (const float4*)lr;
  const int n4 = V >> 2;
  const int q0 = (int)((long long)seg * n4 / SA);
  const int q1 = (int)((long long)(seg + 1) * n4 / SA);
  float mx = -INFINITY;
  if (m0) {
    for (int i = tid; i < NB; i += TAA) cnt[i] = 0;
    if (tid == 0) lcnt = 0;
    __syncthreads();
    for (int i = q0 + tid; i < q1; i += TAA) {
      float4 v = l4[i];
      float xs[4] = {v.x / t, v.y / t, v.z / t, v.w / t};
#pragma unroll
      for (int j = 0; j < 4; ++j) {
        mx = fmaxf(mx, xs[j]);
        atomicAdd(&cnt[f2key(xs[j]) >> 20], 1u);
      }
    }
    if (seg == SA - 1)
      for (int i = (n4 << 2) + tid; i < V; i += TAA) {
        float x = lr[i] / t;
        mx = fmaxf(mx, x);
        atomicAdd(&cnt[f2key(x) >> 20], 1u);
      }
  } else {
    for (int i = q0 + tid; i < q1; i += TAA) {
      float4 v = l4[i];
      mx = fmaxf(mx, fmaxf(fmaxf(v.x, v.y), fmaxf(v.z, v.w)) / t);
    }
    if (seg == SA - 1)
      for (int i = (n4 << 2) + tid; i < V; i += TAA) mx = fmaxf(mx, lr[i] / t);
  }
  sm[tid] = mx;
  __syncthreads();
  for (int s = TAA >> 1; s > 0; s >>= 1) {
    if (tid < s) sm[tid] = fmaxf(sm[tid], sm[tid + s]);
    __syncthreads();
  }
  if (tid == 0) maxpart[row * SA + seg] = sm[0];
  if (!m0) return;
  if (tid < HS) {
    u32 cc = 0; const int base = tid * (NB / HS);
    for (int j = 0; j < NB / HS; ++j) cc += cnt[base + j];
    cs[tid] = cc;
  }
  __syncthreads();
  if (tid == 0) {
    u32 rc = 0;
    for (int c = HS - 1; c >= 0; --c) { u32 tmp = cs[c]; cs[c] = rc; rc += tmp; }
  }
  __syncthreads();
  const int kk = (k > 256) ? 256 : k;
  if (tid < HS) {
    const int base = tid * (NB / HS);
    u32 rc = cs[tid]; int best = -1;
    for (int b = base + NB / HS - 1; b >= base; --b) {
      u32 c = cnt[b];
      if (c && best < 0 && (int)(rc + c) >= kk) best = b;
      rc += c;
    }
    bb[tid] = best;
  }
  __syncthreads();
  if (tid == 0) {
    int bsel = -1;
    for (int c = 0; c < HS; ++c) if (bb[c] > bsel) bsel = bb[c];
    if (bsel < 0) { for (int b = 0; b < NB; ++b) if (cnt[b]) { bsel = b; break; } }
    if (bsel < 0) bsel = 0;
    sT = ((u32)bsel) << 20;
  }
  __syncthreads();
  const u32 T = sT;
  const size_t cbase = ((size_t)row * SA + seg) * CAPSEG;
  for (int i = q0 + tid; i < q1; i += TAA) {
    float4 v = l4[i];
    float xs[4] = {v.x / t, v.y / t, v.z / t, v.w / t};
#pragma unroll
    for (int j = 0; j < 4; ++j) {
      if (f2key(xs[j]) >= T) {
        int s = atomicAdd(&lcnt, 1);
        if (s < CAPSEG) { candv[cbase + s] = xs[j]; candi[cbase + s] = i * 4 + j; }
      }
    }
  }
  if (seg == SA - 1)
    for (int i = (n4 << 2) + tid; i < V; i += TAA) {
      float x = lr[i] / t;
      if (f2key(x) >= T) {
        int s = atomicAdd(&lcnt, 1);
        if (s < CAPSEG) { candv[cbase + s] = x; candi[cbase + s] = i; }
      }
    }
  __syncthreads();
  if (tid == 0) { int n = lcnt; if (n > CAPSEG) n = CAPSEG; scnt[row * SA + seg] = (u32)n; }
}

// kM: entire mode-1 pipeline, seg-parallel, NO solo row passes.
// Seg blocks (per 1/8 row): 12-bit hist + fixed-point esum + per-bin packed
// argmax of rt=exp(x-m)/q (LDS atomicMax -> global atomicMax, associative)
// + bin-sorted scatter of all (x,idx) into this seg's region of g1all (exact
// offsets from an LDS prefix over the local hist; per-seg bin starts published
// to m1sb). Last arriver: hist readback -> scan -> pfx; winners for bins>pfx
// from m1w; boundary (bin==pfx) elements read directly from the 8 scatter
// regions; sub-scan/sort/replay unchanged; final argmax in packed-u64 domain
// ((f2key(rt)<<32)|~idx — order-isomorphic to (rt, smaller idx)).
__global__ __launch_bounds__(TBB) void kM(const float* __restrict__ logits,
                                          const float* __restrict__ temps,
                                          const int* __restrict__ topks,
                                          const float* __restrict__ topps,
                                          const float* __restrict__ noise,
                                          const float* __restrict__ maxpart,
                                          float* __restrict__ Sparts,
                                          u32* __restrict__ m1c0,
                                          u64* __restrict__ m1e0,
                                          u64* __restrict__ m1w,
                                          u32* __restrict__ m1sb,
                                          u64* __restrict__ g1all,
                                          u32* __restrict__ rdoneM,
                                          int* __restrict__ out, int V) {
  const int row = blockIdx.x, seg = blockIdx.y, tid = threadIdx.x;
  const int k = topks[row];
  if (is_mode0(k, V)) return;
  __shared__ int red[128];
  const int slot = m1_slot(topks, row, V, tid, red);
  if (slot >= MAXM1) return;

  __shared__ u32 cnt[NB];        // 16KB (hist, then rank counters, then readback)
  __shared__ u64 e0[NB];         // 32KB
  __shared__ u64 wtab[NB];       // 32KB (winners; reused as u32 lbase after flush)
  __shared__ float ss[TBB];      // 4KB
  __shared__ u32 psc[TBB];       // 4KB (prefix scan)
  __shared__ ScanSh ax;          // 10KB
  __shared__ u32 cnt1[1024]; __shared__ u64 fx1[1024];   // 12KB
  __shared__ u32 csuf[1024]; __shared__ u64 esuf[1024];  // 12KB
  __shared__ float subv[SUBC]; __shared__ int subi[SUBC];
  __shared__ float ssv[SUBC]; __shared__ int ssi[SUBC];  // 8KB
  __shared__ u64 rrp[TBB];       // 8KB
  __shared__ int eqs[EQC];
  __shared__ int segoff[SEG2]; __shared__ int segn[SEG2]; __shared__ int segcum[SEG2 + 1];
  __shared__ u32 spfx; __shared__ int sca; __shared__ float sea;
  __shared__ float sS;
  __shared__ int scross, sfb, sca1, sns, seqn;
  __shared__ float sea1; __shared__ u32 svstar;
  __shared__ int slast;

  const float t = temps[row];
  const float m = row_max(maxpart, row);
  const float* lr = logits + (size_t)row * V;
  const float* ur = noise + (size_t)row * V;
  const float4* l4 = (const float4*)lr;
  const float4* u4 = (const float4*)ur;
  const int n4 = V >> 2;
  const int q0 = (int)((long long)seg * n4 / SEG2);
  const int q1 = (int)((long long)(seg + 1) * n4 / SEG2);
  const int eb0 = q0 << 2;

  for (int i = tid; i < NB; i += TBB) { cnt[i] = 0; e0[i] = 0ull; wtab[i] = 0ull; }
  __syncthreads();

  // ---- pass 1: hist + fixed-point esum + per-bin rt winners + S ----
  float ls = 0.f;
  for (int i = q0 + tid; i < q1; i += TBB) {
    float4 xv = l4[i]; float4 uv = u4[i];
    float xs[4] = {xv.x / t, xv.y / t, xv.z / t, xv.w / t};
    float us[4] = {uv.x, uv.y, uv.z, uv.w};
#pragma unroll
    for (int j = 0; j < 4; ++j) {
      float e = expf(xs[j] - m);
      ls += e;
      u32 b = f2key(xs[j]) >> 20;
      atomicAdd(&cnt[b], 1u);
      u64 fx = (u64)(e * FXS);
      if (fx) atomicAdd(&e0[b], fx);
      float q = fmaxf(-logf(us[j]), 1e-10f);
      float rt = e / q;
      u64 wp = ((u64)f2key(rt) << 32) | (u64)(0xFFFFFFFFu - (u32)(i * 4 + j));
      atomicMax(&wtab[b], wp);
    }
  }
  if (seg == SEG2 - 1)
    for (int i = (n4 << 2) + tid; i < V; i += TBB) {
      float x = lr[i] / t;
      float e = expf(x - m);
      ls += e;
      u32 b = f2key(x) >> 20;
      atomicAdd(&cnt[b], 1u);
      u64 fx = (u64)(e * FXS);
      if (fx) atomicAdd(&e0[b], fx);
      float q = fmaxf(-logf(ur[i]), 1e-10f);
      float rt = e / q;
      u64 wp = ((u64)f2key(rt) << 32) | (u64)(0xFFFFFFFFu - (u32)i);
      atomicMax(&wtab[b], wp);
    }
  ss[tid] = ls;
  __syncthreads();
  for (int s = TBB >> 1; s > 0; s >>= 1) {
    if (tid < s) ss[tid] += ss[tid + s];
    __syncthreads();
  }
  if (tid == 0)
    atomicExch((u32*)&Sparts[slot * SEG2 + seg], __float_as_uint(ss[0]));

  // ---- flush to global accumulators ----
  for (int b = tid; b < NB; b += TBB) {
    u32 c = cnt[b]; if (c) atomicAdd(&m1c0[(size_t)slot * NB + b], c);
    u64 e = e0[b]; if (e) atomicAdd(&m1e0[(size_t)slot * NB + b], e);
    u64 w = wtab[b]; if (w) atomicMax(&m1w[(size_t)slot * NB + b], w);
  }

  // ---- local exclusive prefix over cnt -> bin-sorted scatter offsets ----
  u32 c4[4]; u32 tsum = 0;
#pragma unroll
  for (int j = 0; j < 4; ++j) { c4[j] = cnt[tid * 4 + j]; tsum += c4[j]; }
  psc[tid] = tsum;
  __syncthreads();  // also fences the flush loop above
  for (int stp = 1; stp < TBB; stp <<= 1) {
    u32 v = 0;
    if (tid >= stp) v = psc[tid - stp];
    __syncthreads();
    psc[tid] += v;
    __syncthreads();
  }
  u32* lbase = (u32*)wtab;  // wtab flushed; reuse (first write is after a barrier)
  {
    u32 run = psc[tid] - tsum;
    const size_t sbb = ((size_t)slot * SEG2 + seg) * (size_t)(NB + 1);
#pragma unroll
    for (int j = 0; j < 4; ++j) {
      lbase[tid * 4 + j] = run;
      atomicExch(&m1sb[sbb + (size_t)(tid * 4 + j)], run);
      run += c4[j];
    }
    if (tid == 0) atomicExch(&m1sb[sbb + NB], psc[TBB - 1]);
  }
  __syncthreads();
  for (int i = tid; i < NB; i += TBB) cnt[i] = 0;  // rank counters
  __syncthreads();

  // ---- pass 2: bin-sorted scatter of (x, idx) into this seg's region ----
  const size_t gseg = (size_t)slot * V + (size_t)eb0;
  for (int i = q0 + tid; i < q1; i += TBB) {
    float4 xv = l4[i];
    float xs[4] = {xv.x / t, xv.y / t, xv.z / t, xv.w / t};
#pragma unroll
    for (int j = 0; j < 4; ++j) {
      u32 b = f2key(xs[j]) >> 20;
      u32 r = atomicAdd(&cnt[b], 1u);
      atomicExch(&g1all[gseg + (size_t)(lbase[b] + r)],
                 ((u64)__float_as_uint(xs[j]) << 32) | (u64)(u32)(i * 4 + j));
    }
  }
  if (seg == SEG2 - 1)
    for (int i = (n4 << 2) + tid; i < V; i += TBB) {
      float x = lr[i] / t;
      u32 b = f2key(x) >> 20;
      u32 r = atomicAdd(&cnt[b], 1u);
      atomicExch(&g1all[gseg + (size_t)(lbase[b] + r)],
                 ((u64)__float_as_uint(x) << 32) | (u64)(u32)i);
    }
  __syncthreads();

  // ---- arrival ----
  if (tid == 0) {
    __threadfence();  // release
    u32 arr = atomicAdd(&rdoneM[row], 1u);
    slast = (arr == (u32)(SEG2 - 1)) ? 1 : 0;
  }
  __syncthreads();
  if (!slast) return;
  __threadfence();  // acquire

  // ---- finisher: no row passes ----
  for (int i = tid; i < NB; i += TBB) {
    cnt[i] = atomicAdd(&m1c0[(size_t)slot * NB + i], 0u);
    e0[i] = atomicAdd(&m1e0[(size_t)slot * NB + i], 0ull);
  }
  if (tid == 0) {
    float S = 0.f;
    for (int j = 0; j < SEG2; ++j)
      S += __uint_as_float(atomicAdd((u32*)&Sparts[slot * SEG2 + j], 0u));
    sS = S;
    sns = 0; scross = -1; sfb = 0x7FFFFFFF;
  }
  __syncthreads();
  const float S = sS;
  const float target = topps[row] * S;
  scan_level(cnt, e0, &ax, &spfx, &sca, &sea, target, tid);
  const u32 pfx = spfx;

  // locate the crossing-bin elements inside the 8 scatter regions
  if (tid < SEG2) {
    const int qq0 = (int)((long long)tid * n4 / SEG2);
    const size_t sbb = ((size_t)slot * SEG2 + tid) * (size_t)(NB + 1);
    int st0 = (int)atomicAdd(&m1sb[sbb + pfx], 0u);
    int st1 = (int)atomicAdd(&m1sb[sbb + pfx + 1], 0u);
    segoff[tid] = (qq0 << 2) + st0;
    segn[tid] = st1 - st0;
  }
  __syncthreads();
  if (tid == 0) {
    int c = 0;
    for (int s = 0; s < SEG2; ++s) { segcum[s] = c; c += segn[s]; }
    segcum[SEG2] = c;
  }
  __syncthreads();
  const int nf = segcum[SEG2];
  const size_t gslot = (size_t)slot * V;

  // 10-bit sub-hist + exact suffix sums + crossing sub-bin
  cnt1[tid] = 0; fx1[tid] = 0ull;
  __syncthreads();
  for (int i = tid; i < nf; i += TBB) {
    int s = 0;
    while (i >= segcum[s + 1]) ++s;
    u64 p = atomicAdd(&g1all[gslot + (size_t)(segoff[s] + (i - segcum[s]))], 0ull);
    float x = __uint_as_float((u32)(p >> 32));
    u32 b = (f2key(x) >> 10) & 0x3FFu;
    float e = expf(x - m);
    atomicAdd(&cnt1[b], 1u);
    u64 fx = (u64)(e * FXS);
    if (fx) atomicAdd(&fx1[b], fx);
  }
  __syncthreads();
  csuf[tid] = cnt1[tid]; esuf[tid] = fx1[tid];
  __syncthreads();
  for (int stp = 1; stp < 1024; stp <<= 1) {
    u32 ca_ = 0; u64 ea_ = 0ull;
    if (tid + stp < 1024) { ca_ = csuf[tid + stp]; ea_ = esuf[tid + stp]; }
    __syncthreads();
    csuf[tid] += ca_; esuf[tid] += ea_;
    __syncthreads();
  }
  {
    u32 c = cnt1[tid];
    if (c) {
      float racc = (float)(esuf[tid] - fx1[tid]) * FXI;  // exact suffix above bin
      float ebv = (float)fx1[tid] * FXI;
      if (sea + (racc + ebv) >= target) atomicMax(&scross, tid);
      atomicMin(&sfb, tid);
    }
  }
  __syncthreads();
  if (tid == 0) {
    int cb = scross;
    if (cb < 0) cb = (sfb != 0x7FFFFFFF) ? sfb : 0;
    u32 cAbove = csuf[cb] - cnt1[cb];
    float eAbove = (float)(esuf[cb] - fx1[cb]) * FXI;
    scross = cb;
    sea1 = sea + eAbove;
    sca1 = sca + (int)cAbove;
  }
  __syncthreads();
  const u32 cb = (u32)scross;
  for (int i = tid; i < nf; i += TBB) {
    int s = 0;
    while (i >= segcum[s + 1]) ++s;
    u64 p = atomicAdd(&g1all[gslot + (size_t)(segoff[s] + (i - segcum[s]))], 0ull);
    float x = __uint_as_float((u32)(p >> 32));
    if (((f2key(x) >> 10) & 0x3FFu) == cb) {
      int s2 = atomicAdd(&sns, 1);
      if (s2 < SUBC) { subv[s2] = x; subi[s2] = (int)(u32)(p & 0xFFFFFFFFull); }
    }
  }
  __syncthreads();
  int ns = sns; if (ns > SUBC) ns = SUBC;
  for (int i = tid; i < ns; i += TBB) {
    float v = subv[i]; int ix = subi[i];
    int rank = 0;
    for (int j2 = 0; j2 < ns; ++j2) {
      float vj = subv[j2]; int ij = subi[j2];
      if (vj > v || (vj == v && ij < ix)) rank++;
    }
    ssv[rank] = v; ssi[rank] = ix;
  }
  __syncthreads();
  if (tid == 0) {
    const float p = topps[row];
    float run_n = sea1 / S;
    const int have_above = (sca1 > 0);
    u32 lastkey = 0u; int lastr = 0, laststart = -1, anykept = 0;
    u32 vsel = 0u; int rsel = -1, bstart = 0;
    int j = 0;
    while (j < ns) {
      u32 key = f2key(ssv[j]);
      int c = 1;
      while (j + c < ns && f2key(ssv[j + c]) == key) ++c;
      float e = expf(ssv[j] - m);
      float en = e / S;
      int kept = 0;
      for (int q = 0; q < c; ++q) {
        float nn = run_n + en;
        if (nn < p) { run_n = nn; kept++; } else break;
      }
      if (kept == c) { lastkey = key; lastr = c; laststart = j; anykept = 1; j += c; continue; }
      if (kept > 0) { vsel = key; rsel = kept; bstart = j; }
      else if (anykept) { vsel = lastkey; rsel = lastr; bstart = laststart; }
      else if (have_above) { vsel = key; rsel = 0; bstart = j; }
      else { vsel = key; rsel = 1; bstart = j; }
      break;
    }
    if (rsel < 0) {
      if (anykept) { vsel = lastkey; rsel = lastr; bstart = laststart; }
      else if (ns > 0) {
        vsel = f2key(ssv[0]); bstart = 0;
        rsel = have_above ? 0 : 1;
      } else { vsel = 0u; rsel = 0; bstart = 0; }
    }
    int eqn = rsel;
    if (eqn > EQC) eqn = EQC;
    if (eqn < 0) eqn = 0;
    if (bstart + eqn > ns) eqn = ns - bstart;
    if (eqn < 0) eqn = 0;
    for (int q2 = 0; q2 < eqn; ++q2) eqs[q2] = ssi[bstart + q2];
    seqn = eqn; svstar = vsel;
  }
  __syncthreads();

  // final argmax: per-bin winners above pfx + boundary race over crossing set
  u64 best = 0ull;
  for (int b = (int)pfx + 1 + tid; b < NB; b += TBB) {
    u64 w = atomicAdd(&m1w[(size_t)slot * NB + b], 0ull);
    if (w > best) best = w;
  }
  const u32 vk = svstar;
  const int eqn = seqn;
  for (int i = tid; i < nf; i += TBB) {
    int s = 0;
    while (i >= segcum[s + 1]) ++s;
    u64 p = atomicAdd(&g1all[gslot + (size_t)(segoff[s] + (i - segcum[s]))], 0ull);
    float x = __uint_as_float((u32)(p >> 32));
    int ix = (int)(u32)(p & 0xFFFFFFFFull);
    u32 key = f2key(x);
    bool kept = key > vk;
    if (!kept && key == vk) {
      for (int e = 0; e < eqn; ++e) if (eqs[e] == ix) { kept = true; break; }
    }
    if (kept) {
      float q = fmaxf(-logf(ur[ix]), 1e-10f);
      float rt = expf(x - m) / q;
      u64 wp = ((u64)f2key(rt) << 32) | (u64)(0xFFFFFFFFu - (u32)ix);
      if (wp > best) best = wp;
    }
  }
  rrp[tid] = best;
  __syncthreads();
  for (int s = TBB >> 1; s > 0; s >>= 1) {
    if (tid < s) { if (rrp[tid + s] > rrp[tid]) rrp[tid] = rrp[tid + s]; }
    __syncthreads();
  }
  if (tid == 0)
    out[row] = (rrp[0] != 0ull) ? (int)(0xFFFFFFFFu - (u32)(rrp[0] & 0xFFFFFFFFull)) : 0;
}

// kH: mode-0 finisher, unchanged R3-proven body.
__global__ __launch_bounds__(TBB) void kH(const float* __restrict__ topps,
                                          const float* __restrict__ noise,
                                          const int* __restrict__ topks,
                                          const float* __restrict__ maxpart,
                                          const u32* __restrict__ scnt,
                                          const float* __restrict__ candv,
                                          const int* __restrict__ candi,
                                          int* __restrict__ out, int V) {
  const int row = blockIdx.x, tid = threadIdx.x;
  const int kR = topks[row];
  if (!is_mode0(kR, V)) return;
  __shared__ float gv[GTOT]; __shared__ int gi[GTOT];
  __shared__ float sv[CAPSEG]; __shared__ int si[CAPSEG];
  __shared__ float fv[CAPSEG]; __shared__ int fi[CAPSEG];
  __shared__ float pe[CAPSEG];
  __shared__ float rr[TBB]; __shared__ int ri[TBB];
  __shared__ int offs[SA + 1];
  __shared__ u32 dh[256]; __shared__ u32 dsufx[256];
  __shared__ u32 sPrefix; __shared__ int sRemain, sNf, sDig;
  __shared__ int sJ; __shared__ float sZ2;
  if (tid == 0) {
    int o = 0;
    for (int s = 0; s < SA; ++s) {
      offs[s] = o;
      int c = (int)scnt[row * SA + s];
      if (c > CAPSEG) c = CAPSEG;
      if (c < 0) c = 0;
      o += c;
    }
    offs[SA] = o;
  }
  __syncthreads();
  const int g = offs[SA];
  for (int s = 0; s < SA; ++s) {
    const int o = offs[s], c = offs[s + 1] - o;
    const size_t cbase = ((size_t)row * SA + s) * CAPSEG;
    for (int i = tid; i < c; i += TBB) { gv[o + i] = candv[cbase + i]; gi[o + i] = candi[cbase + i]; }
  }
  __syncthreads();
  int kk = kR; if (kk > 256) kk = 256; if (kk > g) kk = g;
  if (tid == 0) { sPrefix = 0u; sRemain = (kk < 1) ? 1 : kk; }
  __syncthreads();
  for (int pass = 0; pass < 4; ++pass) {
    const int shift = 24 - 8 * pass;
    if (tid < 256) dh[tid] = 0;
    if (tid == 0) sDig = -1;
    __syncthreads();
    const u32 pref = sPrefix;
    for (int i = tid; i < g; i += TBB) {
      u32 key = f2key(gv[i]);
      if (pass == 0 || (key >> (shift + 8)) == pref)
        atomicAdd(&dh[(key >> shift) & 0xFFu], 1u);
    }
    __syncthreads();
    if (tid < 256) dsufx[tid] = dh[tid];
    __syncthreads();
    for (int stp = 1; stp < 256; stp <<= 1) {
      u32 addv = 0;
      if (tid < 256 && tid + stp < 256) addv = dsufx[tid + stp];
      __syncthreads();
      if (tid < 256) dsufx[tid] += addv;
      __syncthreads();
    }
    if (tid < 256) {
      u32 excl = dsufx[tid] - dh[tid];
      u32 rem = (u32)sRemain;
      if (dh[tid] && excl < rem && excl + dh[tid] >= rem) sDig = tid;  // unique
    }
    __syncthreads();
    if (tid == 0) {
      int d = sDig; if (d < 0) d = 0;
      u32 excl = dsufx[d] - dh[d];
      sRemain -= (int)excl;
      sPrefix = (sPrefix << 8) | (u32)d;
      if (pass == 3) sNf = 0;
    }
    __syncthreads();
  }
  const u32 Tk = sPrefix;
  for (int i = tid; i < g; i += TBB) {
    if (f2key(gv[i]) >= Tk) {
      int s = atomicAdd(&sNf, 1);
      if (s < CAPSEG) { fv[s] = gv[i]; fi[s] = gi[i]; }
    }
  }
  __syncthreads();
  int nf = sNf; if (nf > CAPSEG) nf = CAPSEG;
  for (int i = tid; i < nf; i += TBB) {
    float v = fv[i]; int ix = fi[i];
    int rank = 0;
    for (int j = 0; j < nf; ++j) {
      float vj = fv[j]; int ij = fi[j];
      if (vj > v || (vj == v && ij < ix)) rank++;
    }
    sv[rank] = v; si[rank] = ix;
  }
  __syncthreads();
  const float m = row_max(maxpart, row);
  const float p = topps[row];
  int keff = kR; if (keff > nf) keff = nf;
  for (int j = tid; j < keff; j += TBB) pe[j] = expf(sv[j] - m);
  __syncthreads();
  if (tid == 0) {
    int J = 1; float Z2 = 1.f;
    if (nf > 0 && keff > 0) {
      float Zk = 0.f;
      for (int j = 0; j < keff; ++j) Zk += pe[j];
      float c = 0.f; int Jc = 0;
      for (int j = 0; j < keff; ++j) {  // no break: cumsum non-decreasing
        float pr = pe[j] / Zk;
        c += pr;
        if (c < p) Jc++;
      }
      if (Jc < 1) Jc = 1;
      J = Jc;
      Z2 = 0.f;
      for (int j = 0; j < J && j < keff; ++j) Z2 += pe[j];
    }
    sJ = J; sZ2 = Z2;
  }
  __syncthreads();
  const int J = sJ; const float Z2 = sZ2;
  float best = -1.f; int bidx = 0x7FFFFFFF;
  for (int j = tid; j < J && j < nf; j += TBB) {
    int ix = si[j];
    float u = noise[(size_t)row * V + ix];
    float q = fmaxf(-logf(u), 1e-10f);
    float pr = pe[j] / Z2;
    float rt = pr / q;
    if (rt > best || (rt == best && ix < bidx)) { best = rt; bidx = ix; }
  }
  rr[tid] = best; ri[tid] = bidx;
  __syncthreads();
  for (int s = TBB >> 1; s > 0; s >>= 1) {
    if (tid < s) {
      float ov = rr[tid + s]; int oi = ri[tid + s];
      if (ov > rr[tid] || (ov == rr[tid] && oi < ri[tid])) { rr[tid] = ov; ri[tid] = oi; }
    }
    __syncthreads();
  }
  if (tid == 0) out[row] = (nf > 0) ? ri[0] : 0;
}

extern "C" void kernel_launch(void* const* d_in, const int* in_sizes, int n_in,
                              void* d_out, int out_size, void* d_ws, size_t ws_size,
                              hipStream_t stream) {
  const float* logits = (const float*)d_in[0];
  const float* temps = (const float*)d_in[1];
  const int* topks = (const int*)d_in[2];
  const float* topps = (const float*)d_in[3];
  const float* noise = (const float*)d_in[4];
  int* out = (int*)d_out;
  const int B = in_sizes[1];
  const int V = in_sizes[0] / B;
  (void)n_in; (void)out_size; (void)ws_size;

  u32* w = (u32*)d_ws;
  size_t o = 0;
  float* maxpart = (float*)(w + o); o += (size_t)B * SA;
  u32* scnt = w + o; o += (size_t)B * SA;
  float* candv = (float*)(w + o); o += (size_t)B * SA * CAPSEG;
  int* candi = (int*)(w + o); o += (size_t)B * SA * CAPSEG;
  if (o & 1) o += 1;
  const size_t zbase = o;                      // zeroed by kA (grid-stride)
  u32* m1c0 = w + o; o += (size_t)MAXM1 * NB;
  u64* m1e0 = (u64*)(w + o); o += 2 * (size_t)MAXM1 * NB;
  u64* m1w = (u64*)(w + o); o += 2 * (size_t)MAXM1 * NB;
  u32* rdoneM = w + o; o += (size_t)B;
  const size_t zwords = o - zbase;
  float* Sparts = (float*)(w + o); o += (size_t)MAXM1 * SEG2;
  u32* m1sb = w + o; o += (size_t)MAXM1 * SEG2 * (NB + 1);
  if (o & 1) o += 1;
  u64* g1all = (u64*)(w + o); o += 2 * (size_t)MAXM1 * V;

  kA<<<dim3(B, SA), TAA, 0, stream>>>(logits, temps, topks, maxpart, scnt,
                                      candv, candi, w + zbase, zwords, V);
  kM<<<dim3(B, SEG2), TBB, 0, stream>>>(logits, temps, topks, topps, noise, maxpart,
                                        Sparts, m1c0, m1e0, m1w, m1sb, g1all,
                                        rdoneM, out, V);
  kH<<<B, TBB, 0, stream>>>(topps, noise, topks, maxpart, scnt, candv, candi, out, V);
}